// Round 12
// baseline (241.953 us; speedup 1.0000x reference)
//
#include <hip/hip_runtime.h>

#define NN 10000
#define D 128
#define NH 4
#define HD 512   // NH * D
#define ZD 64

__device__ __forceinline__ float lrelu(float x){ return x > 0.0f ? x : 0.2f*x; }

// ---------------- CSR build ----------------
__global__ __launch_bounds__(256) void k_hist(const int* __restrict__ dst,
                                              int* __restrict__ deg, int E){
  int i = blockIdx.x*256 + threadIdx.x;
  if (i < E) atomicAdd(&deg[dst[i]], 1);
}

// single block of 1024: exclusive scan of deg -> ioff, cursor reset, dinv
__global__ __launch_bounds__(1024) void k_scan(int* __restrict__ deg,
                                               int* __restrict__ ioff,
                                               float* __restrict__ dinv){
  __shared__ int part[1024];
  const int tid = threadIdx.x;
  const int base = tid*10;
  int local[10]; int s = 0;
#pragma unroll
  for (int i=0;i<10;i++){
    int idx = base+i;
    int v = (idx < NN) ? deg[idx] : 0;
    if (idx < NN) dinv[idx] = rsqrtf(1.0f + (float)v);
    local[i] = s; s += v;
  }
  part[tid] = s;
  __syncthreads();
  for (int o=1;o<1024;o<<=1){
    int v = (tid>=o) ? part[tid-o] : 0;
    __syncthreads();
    part[tid] += v;
    __syncthreads();
  }
  int excl = part[tid] - s;
#pragma unroll
  for (int i=0;i<10;i++){
    int idx = base+i;
    if (idx < NN){
      int o = excl + local[i];
      ioff[idx] = o;
      deg[idx]  = o;    // cursor reset
    }
  }
  if (tid == 1023) ioff[NN] = part[1023];
}

// fill CSR; also zero a_src/a_dst (contiguous, NN*NH*2 floats)
__global__ __launch_bounds__(256) void k_fill(const int* __restrict__ src,
                                              const int* __restrict__ dst,
                                              int* __restrict__ cur,
                                              int* __restrict__ csr, int E,
                                              float* __restrict__ az){
  int i = blockIdx.x*256 + threadIdx.x;
  if (i < NN*NH*2) az[i] = 0.f;
  if (i >= E) return;
  int pos = atomicAdd(&cur[dst[i]], 1);
  csr[pos] = src[i];
}

// ---------------- mega front kernel: GCN-proj GEMM + watt + icur zero ------
__global__ __launch_bounds__(256) void k_mega(const float* __restrict__ x,
                                              const float* __restrict__ gcn_w,
                                              float* __restrict__ xw,
                                              const float* __restrict__ gat_w,
                                              const float* __restrict__ att_src,
                                              const float* __restrict__ att_dst,
                                              float* __restrict__ w_as,
                                              float* __restrict__ w_ad,
                                              int* __restrict__ icur){
  __shared__ float As[64][132];
  __shared__ float Ws[128][68];
  const int bx  = blockIdx.x;
  const int tid = threadIdx.x;
  if (bx < 314){
    const int row0 = (bx >> 1)*64;
    const int col0 = (bx & 1)*64;
#pragma unroll
    for (int i=0;i<8;i++){
      int f  = tid + i*256;
      int r  = f >> 5;
      int k4 = (f & 31) << 2;
      int rr = row0 + r;
      float4 v = make_float4(0.f,0.f,0.f,0.f);
      if (rr < NN) v = *(const float4*)&x[rr*D + k4];
      *(float4*)&As[r][k4] = v;
    }
#pragma unroll
    for (int i=0;i<8;i++){
      int f  = tid + i*256;
      int k  = f >> 4;
      int c4 = (f & 15) << 2;
      *(float4*)&Ws[k][c4] = *(const float4*)&gcn_w[k*D + col0 + c4];
    }
    __syncthreads();
    const int tx = tid & 15, ty = tid >> 4;
    float acc[4][4] = {{0.f}};
#pragma unroll 4
    for (int k=0;k<128;k++){
      float4 w = *(const float4*)&Ws[k][tx<<2];
      float wv[4] = {w.x, w.y, w.z, w.w};
      float av[4];
#pragma unroll
      for (int i=0;i<4;i++) av[i] = As[(ty<<2)+i][k];
#pragma unroll
      for (int i=0;i<4;i++)
#pragma unroll
        for (int j=0;j<4;j++) acc[i][j] = fmaf(av[i], wv[j], acc[i][j]);
    }
#pragma unroll
    for (int i=0;i<4;i++){
      int r = row0 + (ty<<2) + i;
      if (r >= NN) continue;
#pragma unroll
      for (int j=0;j<4;j++)
        xw[r*D + col0 + (tx<<2) + j] = acc[i][j];
    }
  } else if (bx < 318){
    const int h = bx - 314;
    const int k = tid;
    if (k < 128){
      const float* wrow = &gat_w[k*HD + h*D];
      const float* as   = &att_src[h*D];
      const float* ad   = &att_dst[h*D];
      float s = 0.f, d = 0.f;
#pragma unroll 4
      for (int c=0;c<D;c++){
        float wv = wrow[c];
        s = fmaf(wv, as[c], s);
        d = fmaf(wv, ad[c], d);
      }
      w_as[h*D + k] = s;
      w_ad[h*D + k] = d;
    }
  } else {
    int i = (bx - 318)*256 + tid;
    if (i < NN) icur[i] = 0;
  }
}

// ---------------- GCN gather (XCD-sliced by channel half)
//                  + fused attention-logit partial dots ----------------
__global__ __launch_bounds__(256) void k_gcn_agg(const float* __restrict__ xw,
                                                 const float* __restrict__ dinv,
                                                 const int* __restrict__ ioff,
                                                 const int* __restrict__ csr,
                                                 const float* __restrict__ bias,
                                                 const float* __restrict__ w_as,
                                                 const float* __restrict__ w_ad,
                                                 float* __restrict__ out,
                                                 float* __restrict__ a_src,
                                                 float* __restrict__ a_dst){
  __shared__ float2 snm[4][64];
  const int sub  = blockIdx.x & 7;
  const int ch   = sub >> 2;               // channel half
  const int g    = blockIdx.x >> 3;        // 0..624
  const int wv   = threadIdx.x >> 6;
  const int lane = threadIdx.x & 63;
  const int w    = g*16 + (sub & 3)*4 + wv;   // node < NN
  const int c    = ch*64 + lane;
  const int beg = ioff[w], end = ioff[w+1];
  float din = dinv[w];
  float ax = xw[w*D + c] * din;
  for (int jb = beg; jb < end; jb += 64){
    int cnt = end - jb; if (cnt > 64) cnt = 64;
    if (lane < cnt){
      int s = csr[jb + lane];
      snm[wv][lane] = make_float2(dinv[s], __int_as_float(s));
    }
    __builtin_amdgcn_wave_barrier();
#pragma unroll 4
    for (int l=0; l<cnt; l++){
      float2 t = snm[wv][l];
      int ss = __float_as_int(t.y);
      ax = fmaf(t.x, xw[ss*D + c], ax);
    }
    __builtin_amdgcn_wave_barrier();
  }
  float val = fmaxf(fmaf(ax, din, bias[c]), 0.f);
  out[w*D + c] = val;
  float ps[NH], pd[NH];
#pragma unroll
  for (int h=0;h<NH;h++){
    ps[h] = val * w_as[h*D + c];
    pd[h] = val * w_ad[h*D + c];
  }
#pragma unroll
  for (int o=32;o>0;o>>=1){
#pragma unroll
    for (int h=0;h<NH;h++){
      ps[h] += __shfl_xor(ps[h], o);
      pd[h] += __shfl_xor(pd[h], o);
    }
  }
  if (lane == 0){
#pragma unroll
    for (int h=0;h<NH;h++){
      atomicAdd(&a_src[w*4 + h], ps[h]);
      atomicAdd(&a_dst[w*4 + h], pd[h]);
    }
  }
}

// ---------------- GAT gather in h1-space: XCD-sliced by channel half ------
__global__ __launch_bounds__(256) void k_gat_agg2(const float* __restrict__ h1,
                                                  const float* __restrict__ a_src,
                                                  const float* __restrict__ a_dst,
                                                  const int* __restrict__ ioff,
                                                  const int* __restrict__ csr,
                                                  float* __restrict__ agg){
  __shared__ float4 sal[4][64];
  __shared__ int    ssr[4][64];
  const int sub  = blockIdx.x & 7;
  const int ch   = sub >> 2;               // channel half
  const int g    = blockIdx.x >> 3;        // 0..624
  const int wv   = threadIdx.x >> 6;
  const int lane = threadIdx.x & 63;
  const int w    = g*16 + (sub & 3)*4 + wv;   // node < NN
  const int c    = ch*64 + lane;
  const int beg = ioff[w], end = ioff[w+1];
  float4 ad  = *(const float4*)&a_dst[w*4];
  float4 asn = *(const float4*)&a_src[w*4];
  float e0 = __expf(lrelu(asn.x + ad.x));
  float e1 = __expf(lrelu(asn.y + ad.y));
  float e2 = __expf(lrelu(asn.z + ad.z));
  float e3 = __expf(lrelu(asn.w + ad.w));
  float hv = h1[w*D + c];
  float o0 = e0*hv, o1 = e1*hv, o2 = e2*hv, o3 = e3*hv;
  float den0=0.f, den1=0.f, den2=0.f, den3=0.f;   // self added after reduce

  for (int jb = beg; jb < end; jb += 64){
    int cnt = end - jb; if (cnt > 64) cnt = 64;
    if (lane < cnt){
      int s = csr[jb + lane];
      float4 as = *(const float4*)&a_src[s*4];
      float g0 = __expf(lrelu(as.x + ad.x));
      float g1 = __expf(lrelu(as.y + ad.y));
      float g2 = __expf(lrelu(as.z + ad.z));
      float g3 = __expf(lrelu(as.w + ad.w));
      sal[wv][lane] = make_float4(g0,g1,g2,g3);
      ssr[wv][lane] = s;
      den0 += g0; den1 += g1; den2 += g2; den3 += g3;
    }
    __builtin_amdgcn_wave_barrier();
#pragma unroll 4
    for (int l=0; l<cnt; l++){
      float4 b = sal[wv][l];
      float sv = h1[ssr[wv][l]*D + c];
      o0 = fmaf(b.x, sv, o0);
      o1 = fmaf(b.y, sv, o1);
      o2 = fmaf(b.z, sv, o2);
      o3 = fmaf(b.w, sv, o3);
    }
    __builtin_amdgcn_wave_barrier();
  }
#pragma unroll
  for (int o=32; o>0; o>>=1){
    den0 += __shfl_xor(den0, o);
    den1 += __shfl_xor(den1, o);
    den2 += __shfl_xor(den2, o);
    den3 += __shfl_xor(den3, o);
  }
  den0 += e0; den1 += e1; den2 += e2; den3 += e3;
  float* ab = &agg[(size_t)w*HD + c];
  ab[0*D] = o0 * (0.25f/den0);
  ab[1*D] = o1 * (0.25f/den1);
  ab[2*D] = o2 * (0.25f/den2);
  ab[3*D] = o3 * (0.25f/den3);
}

// ---------------- Fused GAT projection + MLP + heads ----------------
// 128 threads, 16-row tile, full 128-col span per phase. Thread = 4 rows x 4
// cols (tx=tid&31 -> cols tx*4, ty=tid>>5 -> rows ty*4). Per k-iter: 1 b128
// Ws read + 4 broadcast S reads feed 16 FMA -> VALU-bound.
// LDS = S 8.4 KB + Ws 67.6 KB = 74.3 KB -> 2 blocks/CU. Grid = 625.
#define KLOOP                                                   \
  _Pragma("unroll 4")                                           \
  for (int k=0;k<128;k++){                                      \
    float4 wv = *(const float4*)&Ws[k][tx<<2];                  \
    float a0 = S[(ty<<2)+0][k];                                 \
    float a1 = S[(ty<<2)+1][k];                                 \
    float a2 = S[(ty<<2)+2][k];                                 \
    float a3 = S[(ty<<2)+3][k];                                 \
    acc[0][0]=fmaf(a0,wv.x,acc[0][0]); acc[0][1]=fmaf(a0,wv.y,acc[0][1]); \
    acc[0][2]=fmaf(a0,wv.z,acc[0][2]); acc[0][3]=fmaf(a0,wv.w,acc[0][3]); \
    acc[1][0]=fmaf(a1,wv.x,acc[1][0]); acc[1][1]=fmaf(a1,wv.y,acc[1][1]); \
    acc[1][2]=fmaf(a1,wv.z,acc[1][2]); acc[1][3]=fmaf(a1,wv.w,acc[1][3]); \
    acc[2][0]=fmaf(a2,wv.x,acc[2][0]); acc[2][1]=fmaf(a2,wv.y,acc[2][1]); \
    acc[2][2]=fmaf(a2,wv.z,acc[2][2]); acc[2][3]=fmaf(a2,wv.w,acc[2][3]); \
    acc[3][0]=fmaf(a3,wv.x,acc[3][0]); acc[3][1]=fmaf(a3,wv.y,acc[3][1]); \
    acc[3][2]=fmaf(a3,wv.z,acc[3][2]); acc[3][3]=fmaf(a3,wv.w,acc[3][3]); \
  }

__global__ __launch_bounds__(128) void k_gat_mlp(const float* __restrict__ agg,
                                                 const float* __restrict__ gat_w,
                                                 const float* __restrict__ gat_b,
                                                 const float* __restrict__ w1,
                                                 const float* __restrict__ b1,
                                                 const float* __restrict__ w2,
                                                 const float* __restrict__ b2,
                                                 const float* __restrict__ wmu,
                                                 const float* __restrict__ bmu,
                                                 const float* __restrict__ wlv,
                                                 const float* __restrict__ blv,
                                                 float* __restrict__ out){
  __shared__ float S[16][132];
  __shared__ float Ws[128][132];
  const int tid  = threadIdx.x;      // 0..127
  const int tx   = tid & 31;         // col group (4 cols of 128)
  const int ty   = tid >> 5;         // 0..3: row group (4 rows of 16)
  const int row0 = blockIdx.x*16;    // NN = 16*625 exactly
  float acc[4][4] = {{0.f}};

  // ---- Phase A: h2 = sum_h agg_h @ W_h (acc carries across heads) ----
  for (int h=0; h<NH; h++){
    __syncthreads();                 // prior KLOOP reads done
#pragma unroll
    for (int i=0;i<4;i++){           // stage S: 512 float4
      int f  = tid + i*128;
      int r  = f >> 5;
      int k4 = (f & 31) << 2;
      *(float4*)&S[r][k4] = *(const float4*)&agg[(size_t)(row0+r)*HD + h*D + k4];
    }
#pragma unroll
    for (int i=0;i<32;i++){          // stage Ws: 4096 float4
      int f  = tid + i*128;
      int k  = f >> 5;
      int c4 = (f & 31) << 2;
      *(float4*)&Ws[k][c4] = *(const float4*)&gat_w[k*HD + h*D + c4];
    }
    __syncthreads();
    KLOOP
  }
  __syncthreads();                   // KLOOP reads of S done
#pragma unroll
  for (int i=0;i<4;i++)
#pragma unroll
    for (int j=0;j<4;j++){
      int c = (tx<<2) + j;
      S[(ty<<2)+i][c] = fmaxf(acc[i][j] + gat_b[c], 0.f);
      acc[i][j] = 0.f;
    }

  // ---- Phase B: two MLP layers in place ----
  for (int layer=0; layer<2; layer++){
    const float* W  = layer ? w2 : w1;
    const float* bb = layer ? b2 : b1;
    __syncthreads();                 // S writes visible; old Ws reads done
#pragma unroll
    for (int i=0;i<32;i++){
      int f  = tid + i*128;
      int k  = f >> 5;
      int c4 = (f & 31) << 2;
      *(float4*)&Ws[k][c4] = *(const float4*)&W[k*D + c4];
    }
    __syncthreads();
    KLOOP
    __syncthreads();                 // reads of S done before overwrite
#pragma unroll
    for (int i=0;i<4;i++)
#pragma unroll
      for (int j=0;j<4;j++){
        int c = (tx<<2) + j;
        S[(ty<<2)+i][c] = fmaxf(acc[i][j] + bb[c], 0.f);
        acc[i][j] = 0.f;
      }
  }

  // ---- Phase C: mu | lv heads in one 128-col phase ----
  __syncthreads();                   // S writes visible
#pragma unroll
  for (int i=0;i<32;i++){
    int f  = tid + i*128;
    int k  = f >> 5;
    int c4 = (f & 31) << 2;
    const float* Wp = (c4 < ZD) ? &wmu[k*ZD + c4] : &wlv[k*ZD + (c4 - ZD)];
    *(float4*)&Ws[k][c4] = *(const float4*)Wp;
  }
  __syncthreads();
  KLOOP
  {
    const int hd = tx >> 4;                 // 0 = mu, 1 = lv
    const int cl = (tx & 15) << 2;          // local col in head
    const float* bb = hd ? blv : bmu;
    float* ob = out + (size_t)hd*NN*ZD;
#pragma unroll
    for (int i=0;i<4;i++){
      int r = row0 + (ty<<2) + i;
      float4 v = make_float4(acc[i][0] + bb[cl+0],
                             acc[i][1] + bb[cl+1],
                             acc[i][2] + bb[cl+2],
                             acc[i][3] + bb[cl+3]);
      *(float4*)&ob[r*ZD + cl] = v;
    }
  }
}

extern "C" void kernel_launch(void* const* d_in, const int* in_sizes, int n_in,
                              void* d_out, int out_size, void* d_ws, size_t ws_size,
                              hipStream_t stream){
  const float* x     = (const float*)d_in[0];
  const int*   ei    = (const int*)d_in[1];
  const float* gcn_w = (const float*)d_in[2];
  const float* gcn_b = (const float*)d_in[3];
  const float* gat_w = (const float*)d_in[4];
  const float* att_s = (const float*)d_in[5];
  const float* att_d = (const float*)d_in[6];
  const float* gat_b = (const float*)d_in[7];
  const float* w1    = (const float*)d_in[8];
  const float* b1    = (const float*)d_in[9];
  const float* w2    = (const float*)d_in[10];
  const float* b2    = (const float*)d_in[11];
  const float* mu_w  = (const float*)d_in[12];
  const float* mu_b  = (const float*)d_in[13];
  const float* lv_w  = (const float*)d_in[14];
  const float* lv_b  = (const float*)d_in[15];
  const int E = in_sizes[1] / 2;
  const int* src = ei;
  const int* dst = ei + E;

  float* ws    = (float*)d_ws;
  float* xw    = ws;                 // N*128 (GCN projection)
  float* h1    = xw + NN*D;          // N*128 (GCN output)
  float* agg   = h1 + NN*D;          // N*512 (per-head h1-space aggregates)
  float* dinv  = agg + (size_t)NN*HD;// N
  float* w_as  = dinv + NN;          // 512
  float* w_ad  = w_as + HD;          // 512
  float* a_src = w_ad + HD;          // N*4
  float* a_dst = a_src + NN*NH;      // N*4 (contiguous with a_src)
  int*   ioff  = (int*)(a_dst + NN*NH);  // N+1
  int*   icur  = ioff + NN + 1;          // N
  int*   csr   = icur + NN;              // E

  const int gE = (E + 255)/256;

  // front: GCN-proj GEMM + watt + icur zero (merged, independent work)
  k_mega<<<358, 256, 0, stream>>>(x, gcn_w, xw, gat_w, att_s, att_d,
                                  w_as, w_ad, icur);
  // CSR build
  k_hist<<<gE, 256, 0, stream>>>(dst, icur, E);
  k_scan<<<1, 1024, 0, stream>>>(icur, ioff, dinv);
  k_fill<<<gE, 256, 0, stream>>>(src, dst, icur, csr, E, a_src);

  // GCN gather (+ fused attention logits)
  k_gcn_agg<<<(NN/16)*8, 256, 0, stream>>>(xw, dinv, ioff, csr, gcn_b,
                                           w_as, w_ad, h1, a_src, a_dst);
  // GAT gather in h1-space
  k_gat_agg2<<<(NN/16)*8, 256, 0, stream>>>(h1, a_src, a_dst, ioff, csr, agg);
  // GAT projection + MLP + heads, fused (4x4 register tiles, grid 625)
  k_gat_mlp<<<NN/16, 128, 0, stream>>>(agg, gat_w, gat_b, w1, b1, w2, b2,
                                       mu_w, mu_b, lv_w, lv_b, (float*)d_out);
}

// Round 13
// 179.494 us; speedup vs baseline: 1.3480x; 1.3480x over previous
//
#include <hip/hip_runtime.h>

#define NN 10000
#define D 128
#define NH 4
#define HD 512   // NH * D
#define ZD 64

__device__ __forceinline__ float lrelu(float x){ return x > 0.0f ? x : 0.2f*x; }

// ---------------- CSR build ----------------
__global__ __launch_bounds__(256) void k_hist(const int* __restrict__ dst,
                                              int* __restrict__ deg, int E){
  int i = blockIdx.x*256 + threadIdx.x;
  if (i < E) atomicAdd(&deg[dst[i]], 1);
}

// single block of 1024: exclusive scan of deg -> ioff, cursor reset, dinv
__global__ __launch_bounds__(1024) void k_scan(int* __restrict__ deg,
                                               int* __restrict__ ioff,
                                               float* __restrict__ dinv){
  __shared__ int part[1024];
  const int tid = threadIdx.x;
  const int base = tid*10;
  int local[10]; int s = 0;
#pragma unroll
  for (int i=0;i<10;i++){
    int idx = base+i;
    int v = (idx < NN) ? deg[idx] : 0;
    if (idx < NN) dinv[idx] = rsqrtf(1.0f + (float)v);
    local[i] = s; s += v;
  }
  part[tid] = s;
  __syncthreads();
  for (int o=1;o<1024;o<<=1){
    int v = (tid>=o) ? part[tid-o] : 0;
    __syncthreads();
    part[tid] += v;
    __syncthreads();
  }
  int excl = part[tid] - s;
#pragma unroll
  for (int i=0;i<10;i++){
    int idx = base+i;
    if (idx < NN){
      int o = excl + local[i];
      ioff[idx] = o;
      deg[idx]  = o;    // cursor reset
    }
  }
  if (tid == 1023) ioff[NN] = part[1023];
}

// fill CSR; also zero a_src/a_dst (contiguous, NN*NH*2 floats)
__global__ __launch_bounds__(256) void k_fill(const int* __restrict__ src,
                                              const int* __restrict__ dst,
                                              int* __restrict__ cur,
                                              int* __restrict__ csr, int E,
                                              float* __restrict__ az){
  int i = blockIdx.x*256 + threadIdx.x;
  if (i < NN*NH*2) az[i] = 0.f;
  if (i >= E) return;
  int pos = atomicAdd(&cur[dst[i]], 1);
  csr[pos] = src[i];
}

// ---------------- mega front kernel: GCN-proj GEMM + watt + icur zero ------
__global__ __launch_bounds__(256) void k_mega(const float* __restrict__ x,
                                              const float* __restrict__ gcn_w,
                                              float* __restrict__ xw,
                                              const float* __restrict__ gat_w,
                                              const float* __restrict__ att_src,
                                              const float* __restrict__ att_dst,
                                              float* __restrict__ w_as,
                                              float* __restrict__ w_ad,
                                              int* __restrict__ icur){
  __shared__ float As[64][132];
  __shared__ float Ws[128][68];
  const int bx  = blockIdx.x;
  const int tid = threadIdx.x;
  if (bx < 314){
    const int row0 = (bx >> 1)*64;
    const int col0 = (bx & 1)*64;
#pragma unroll
    for (int i=0;i<8;i++){
      int f  = tid + i*256;
      int r  = f >> 5;
      int k4 = (f & 31) << 2;
      int rr = row0 + r;
      float4 v = make_float4(0.f,0.f,0.f,0.f);
      if (rr < NN) v = *(const float4*)&x[rr*D + k4];
      *(float4*)&As[r][k4] = v;
    }
#pragma unroll
    for (int i=0;i<8;i++){
      int f  = tid + i*256;
      int k  = f >> 4;
      int c4 = (f & 15) << 2;
      *(float4*)&Ws[k][c4] = *(const float4*)&gcn_w[k*D + col0 + c4];
    }
    __syncthreads();
    const int tx = tid & 15, ty = tid >> 4;
    float acc[4][4] = {{0.f}};
#pragma unroll 4
    for (int k=0;k<128;k++){
      float4 w = *(const float4*)&Ws[k][tx<<2];
      float wv[4] = {w.x, w.y, w.z, w.w};
      float av[4];
#pragma unroll
      for (int i=0;i<4;i++) av[i] = As[(ty<<2)+i][k];
#pragma unroll
      for (int i=0;i<4;i++)
#pragma unroll
        for (int j=0;j<4;j++) acc[i][j] = fmaf(av[i], wv[j], acc[i][j]);
    }
#pragma unroll
    for (int i=0;i<4;i++){
      int r = row0 + (ty<<2) + i;
      if (r >= NN) continue;
#pragma unroll
      for (int j=0;j<4;j++)
        xw[r*D + col0 + (tx<<2) + j] = acc[i][j];
    }
  } else if (bx < 318){
    const int h = bx - 314;
    const int k = tid;
    if (k < 128){
      const float* wrow = &gat_w[k*HD + h*D];
      const float* as   = &att_src[h*D];
      const float* ad   = &att_dst[h*D];
      float s = 0.f, d = 0.f;
#pragma unroll 4
      for (int c=0;c<D;c++){
        float wv = wrow[c];
        s = fmaf(wv, as[c], s);
        d = fmaf(wv, ad[c], d);
      }
      w_as[h*D + k] = s;
      w_ad[h*D + k] = d;
    }
  } else {
    int i = (bx - 318)*256 + tid;
    if (i < NN) icur[i] = 0;
  }
}

// ---------------- GCN gather (XCD-sliced by channel half)
//                  + fused attention-logit partial dots ----------------
__global__ __launch_bounds__(256) void k_gcn_agg(const float* __restrict__ xw,
                                                 const float* __restrict__ dinv,
                                                 const int* __restrict__ ioff,
                                                 const int* __restrict__ csr,
                                                 const float* __restrict__ bias,
                                                 const float* __restrict__ w_as,
                                                 const float* __restrict__ w_ad,
                                                 float* __restrict__ out,
                                                 float* __restrict__ a_src,
                                                 float* __restrict__ a_dst){
  __shared__ float2 snm[4][64];
  const int sub  = blockIdx.x & 7;
  const int ch   = sub >> 2;               // channel half
  const int g    = blockIdx.x >> 3;        // 0..624
  const int wv   = threadIdx.x >> 6;
  const int lane = threadIdx.x & 63;
  const int w    = g*16 + (sub & 3)*4 + wv;   // node < NN
  const int c    = ch*64 + lane;
  const int beg = ioff[w], end = ioff[w+1];
  float din = dinv[w];
  float ax = xw[w*D + c] * din;
  for (int jb = beg; jb < end; jb += 64){
    int cnt = end - jb; if (cnt > 64) cnt = 64;
    if (lane < cnt){
      int s = csr[jb + lane];
      snm[wv][lane] = make_float2(dinv[s], __int_as_float(s));
    }
    __builtin_amdgcn_wave_barrier();
#pragma unroll 4
    for (int l=0; l<cnt; l++){
      float2 t = snm[wv][l];
      int ss = __float_as_int(t.y);
      ax = fmaf(t.x, xw[ss*D + c], ax);
    }
    __builtin_amdgcn_wave_barrier();
  }
  float val = fmaxf(fmaf(ax, din, bias[c]), 0.f);
  out[w*D + c] = val;
  float ps[NH], pd[NH];
#pragma unroll
  for (int h=0;h<NH;h++){
    ps[h] = val * w_as[h*D + c];
    pd[h] = val * w_ad[h*D + c];
  }
#pragma unroll
  for (int o=32;o>0;o>>=1){
#pragma unroll
    for (int h=0;h<NH;h++){
      ps[h] += __shfl_xor(ps[h], o);
      pd[h] += __shfl_xor(pd[h], o);
    }
  }
  if (lane == 0){
#pragma unroll
    for (int h=0;h<NH;h++){
      atomicAdd(&a_src[w*4 + h], ps[h]);
      atomicAdd(&a_dst[w*4 + h], pd[h]);
    }
  }
}

// ---------------- GAT gather in h1-space: XCD-sliced by channel half ------
__global__ __launch_bounds__(256) void k_gat_agg2(const float* __restrict__ h1,
                                                  const float* __restrict__ a_src,
                                                  const float* __restrict__ a_dst,
                                                  const int* __restrict__ ioff,
                                                  const int* __restrict__ csr,
                                                  float* __restrict__ agg){
  __shared__ float4 sal[4][64];
  __shared__ int    ssr[4][64];
  const int sub  = blockIdx.x & 7;
  const int ch   = sub >> 2;               // channel half
  const int g    = blockIdx.x >> 3;        // 0..624
  const int wv   = threadIdx.x >> 6;
  const int lane = threadIdx.x & 63;
  const int w    = g*16 + (sub & 3)*4 + wv;   // node < NN
  const int c    = ch*64 + lane;
  const int beg = ioff[w], end = ioff[w+1];
  float4 ad  = *(const float4*)&a_dst[w*4];
  float4 asn = *(const float4*)&a_src[w*4];
  float e0 = __expf(lrelu(asn.x + ad.x));
  float e1 = __expf(lrelu(asn.y + ad.y));
  float e2 = __expf(lrelu(asn.z + ad.z));
  float e3 = __expf(lrelu(asn.w + ad.w));
  float hv = h1[w*D + c];
  float o0 = e0*hv, o1 = e1*hv, o2 = e2*hv, o3 = e3*hv;
  float den0=0.f, den1=0.f, den2=0.f, den3=0.f;   // self added after reduce

  for (int jb = beg; jb < end; jb += 64){
    int cnt = end - jb; if (cnt > 64) cnt = 64;
    if (lane < cnt){
      int s = csr[jb + lane];
      float4 as = *(const float4*)&a_src[s*4];
      float g0 = __expf(lrelu(as.x + ad.x));
      float g1 = __expf(lrelu(as.y + ad.y));
      float g2 = __expf(lrelu(as.z + ad.z));
      float g3 = __expf(lrelu(as.w + ad.w));
      sal[wv][lane] = make_float4(g0,g1,g2,g3);
      ssr[wv][lane] = s;
      den0 += g0; den1 += g1; den2 += g2; den3 += g3;
    }
    __builtin_amdgcn_wave_barrier();
#pragma unroll 4
    for (int l=0; l<cnt; l++){
      float4 b = sal[wv][l];
      float sv = h1[ssr[wv][l]*D + c];
      o0 = fmaf(b.x, sv, o0);
      o1 = fmaf(b.y, sv, o1);
      o2 = fmaf(b.z, sv, o2);
      o3 = fmaf(b.w, sv, o3);
    }
    __builtin_amdgcn_wave_barrier();
  }
#pragma unroll
  for (int o=32; o>0; o>>=1){
    den0 += __shfl_xor(den0, o);
    den1 += __shfl_xor(den1, o);
    den2 += __shfl_xor(den2, o);
    den3 += __shfl_xor(den3, o);
  }
  den0 += e0; den1 += e1; den2 += e2; den3 += e3;
  float* ab = &agg[(size_t)w*HD + c];
  ab[0*D] = o0 * (0.25f/den0);
  ab[1*D] = o1 * (0.25f/den1);
  ab[2*D] = o2 * (0.25f/den2);
  ab[3*D] = o3 * (0.25f/den3);
}

// ---------------- Fused GAT projection + MLP + heads ----------------
// Weights read DIRECTLY from global (L2-resident ~450KB total); only the
// 16x128 activation tile lives in LDS (8.4 KB). S read as b128 along k.
// 128 threads: tx=tid&31 -> 4 cols (c0=tx*4), ty=tid>>5 -> 4 rows (r0=ty*4).
// Per 4-k group/thread: 4 global b128 (W) + 4 LDS b128 (S) + 64 FMA
// -> VALU-bound; LDS pipe ~48cyc << VALU 128cyc; W traffic 0.5 B/FLOP < L2 BW.
#define KLOOP4(WB, LDW)                                                     \
  _Pragma("unroll 2")                                                       \
  for (int k4=0; k4<128; k4+=4){                                            \
    float4 w0 = *(const float4*)&(WB)[(k4+0)*(LDW)];                        \
    float4 w1 = *(const float4*)&(WB)[(k4+1)*(LDW)];                        \
    float4 w2 = *(const float4*)&(WB)[(k4+2)*(LDW)];                        \
    float4 w3 = *(const float4*)&(WB)[(k4+3)*(LDW)];                        \
    _Pragma("unroll")                                                       \
    for (int i=0;i<4;i++){                                                  \
      float4 sv = *(const float4*)&S[r0+i][k4];                             \
      acc[i][0]=fmaf(sv.w,w3.x,fmaf(sv.z,w2.x,fmaf(sv.y,w1.x,fmaf(sv.x,w0.x,acc[i][0])))); \
      acc[i][1]=fmaf(sv.w,w3.y,fmaf(sv.z,w2.y,fmaf(sv.y,w1.y,fmaf(sv.x,w0.y,acc[i][1])))); \
      acc[i][2]=fmaf(sv.w,w3.z,fmaf(sv.z,w2.z,fmaf(sv.y,w1.z,fmaf(sv.x,w0.z,acc[i][2])))); \
      acc[i][3]=fmaf(sv.w,w3.w,fmaf(sv.z,w2.w,fmaf(sv.y,w1.w,fmaf(sv.x,w0.w,acc[i][3])))); \
    }                                                                       \
  }

__global__ __launch_bounds__(128) void k_gat_mlp(const float* __restrict__ agg,
                                                 const float* __restrict__ gat_w,
                                                 const float* __restrict__ gat_b,
                                                 const float* __restrict__ w1,
                                                 const float* __restrict__ b1,
                                                 const float* __restrict__ w2,
                                                 const float* __restrict__ b2,
                                                 const float* __restrict__ wmu,
                                                 const float* __restrict__ bmu,
                                                 const float* __restrict__ wlv,
                                                 const float* __restrict__ blv,
                                                 float* __restrict__ out){
  __shared__ float S[16][132];
  const int tid  = threadIdx.x;      // 0..127
  const int tx   = tid & 31;
  const int ty   = tid >> 5;         // 0..3
  const int c0   = tx << 2;
  const int r0   = ty << 2;
  const int row0 = blockIdx.x*16;    // NN = 16*625 exactly
  float acc[4][4] = {{0.f}};

  // ---- Phase A: h2 = sum_h agg_h @ W_h (acc carries across heads) ----
  for (int h=0; h<NH; h++){
    __syncthreads();                 // prior KLOOP reads of S done
#pragma unroll
    for (int i=0;i<4;i++){           // stage S: 512 float4, 4 per thread
      int f  = tid + i*128;
      int r  = f >> 5;
      int k4 = (f & 31) << 2;
      *(float4*)&S[r][k4] = *(const float4*)&agg[(size_t)(row0+r)*HD + h*D + k4];
    }
    __syncthreads();
    const float* Wb = &gat_w[h*D + c0];
    KLOOP4(Wb, HD)
  }
  __syncthreads();                   // KLOOP reads of S done
#pragma unroll
  for (int i=0;i<4;i++)
#pragma unroll
    for (int j=0;j<4;j++){
      S[r0+i][c0+j] = fmaxf(acc[i][j] + gat_b[c0+j], 0.f);
      acc[i][j] = 0.f;
    }

  // ---- Phase B: two MLP layers in place ----
  for (int layer=0; layer<2; layer++){
    const float* W  = layer ? w2 : w1;
    const float* bb = layer ? b2 : b1;
    __syncthreads();                 // S writes visible
    const float* Wb = &W[c0];
    KLOOP4(Wb, D)
    __syncthreads();                 // reads of S done before overwrite
#pragma unroll
    for (int i=0;i<4;i++)
#pragma unroll
      for (int j=0;j<4;j++){
        S[r0+i][c0+j] = fmaxf(acc[i][j] + bb[c0+j], 0.f);
        acc[i][j] = 0.f;
      }
  }

  // ---- Phase C: mu | lv heads in one pass (tx<16 -> mu, else lv) ----
  __syncthreads();                   // S writes visible
  {
    const int hd = tx >> 4;
    const int cl = (tx & 15) << 2;
    const float* Wb = (hd ? &wlv[cl] : &wmu[cl]);
    const float* bb = hd ? blv : bmu;
    float* ob = out + (size_t)hd*NN*ZD;
    KLOOP4(Wb, ZD)
#pragma unroll
    for (int i=0;i<4;i++){
      int r = row0 + r0 + i;
      float4 v = make_float4(acc[i][0] + bb[cl+0],
                             acc[i][1] + bb[cl+1],
                             acc[i][2] + bb[cl+2],
                             acc[i][3] + bb[cl+3]);
      *(float4*)&ob[r*ZD + cl] = v;
    }
  }
}

extern "C" void kernel_launch(void* const* d_in, const int* in_sizes, int n_in,
                              void* d_out, int out_size, void* d_ws, size_t ws_size,
                              hipStream_t stream){
  const float* x     = (const float*)d_in[0];
  const int*   ei    = (const int*)d_in[1];
  const float* gcn_w = (const float*)d_in[2];
  const float* gcn_b = (const float*)d_in[3];
  const float* gat_w = (const float*)d_in[4];
  const float* att_s = (const float*)d_in[5];
  const float* att_d = (const float*)d_in[6];
  const float* gat_b = (const float*)d_in[7];
  const float* w1    = (const float*)d_in[8];
  const float* b1    = (const float*)d_in[9];
  const float* w2    = (const float*)d_in[10];
  const float* b2    = (const float*)d_in[11];
  const float* mu_w  = (const float*)d_in[12];
  const float* mu_b  = (const float*)d_in[13];
  const float* lv_w  = (const float*)d_in[14];
  const float* lv_b  = (const float*)d_in[15];
  const int E = in_sizes[1] / 2;
  const int* src = ei;
  const int* dst = ei + E;

  float* ws    = (float*)d_ws;
  float* xw    = ws;                 // N*128 (GCN projection)
  float* h1    = xw + NN*D;          // N*128 (GCN output)
  float* agg   = h1 + NN*D;          // N*512 (per-head h1-space aggregates)
  float* dinv  = agg + (size_t)NN*HD;// N
  float* w_as  = dinv + NN;          // 512
  float* w_ad  = w_as + HD;          // 512
  float* a_src = w_ad + HD;          // N*4
  float* a_dst = a_src + NN*NH;      // N*4 (contiguous with a_src)
  int*   ioff  = (int*)(a_dst + NN*NH);  // N+1
  int*   icur  = ioff + NN + 1;          // N
  int*   csr   = icur + NN;              // E

  const int gE = (E + 255)/256;

  // front: GCN-proj GEMM + watt + icur zero (merged, independent work)
  k_mega<<<358, 256, 0, stream>>>(x, gcn_w, xw, gat_w, att_s, att_d,
                                  w_as, w_ad, icur);
  // CSR build
  k_hist<<<gE, 256, 0, stream>>>(dst, icur, E);
  k_scan<<<1, 1024, 0, stream>>>(icur, ioff, dinv);
  k_fill<<<gE, 256, 0, stream>>>(src, dst, icur, csr, E, a_src);

  // GCN gather (+ fused attention logits)
  k_gcn_agg<<<(NN/16)*8, 256, 0, stream>>>(xw, dinv, ioff, csr, gcn_b,
                                           w_as, w_ad, h1, a_src, a_dst);
  // GAT gather in h1-space
  k_gat_agg2<<<(NN/16)*8, 256, 0, stream>>>(h1, a_src, a_dst, ioff, csr, agg);
  // GAT projection + MLP + heads, fused (weights from L2, S-only LDS)
  k_gat_mlp<<<NN/16, 128, 0, stream>>>(agg, gat_w, gat_b, w1, b1, w2, b2,
                                       mu_w, mu_b, lv_w, lv_b, (float*)d_out);
}